// Round 4
// baseline (414.200 us; speedup 1.0000x reference)
//
#include <hip/hip_runtime.h>
#include <hip/hip_bf16.h>
#include <math.h>

#define N 8192
#define F 133
#define FP 136
#define H 256
#define MF 200
#define RH 512
#define DEPTH 3
#define MAXDEG 128
#define NRO_BLOCKS 8

typedef unsigned short bfu;

static __device__ __forceinline__ bfu f2bf(float f) {
    unsigned u = __builtin_bit_cast(unsigned, f);
    u = (u + 0x7fff + ((u >> 16) & 1)) >> 16;   // RNE, finite inputs
    return (bfu)u;
}
static __device__ __forceinline__ float bf2f(bfu b) {
    unsigned u = (unsigned)b << 16;
    return __builtin_bit_cast(float, u);
}

// ---------------- h0 = X @ W_in + b_in  -> bf16 ----------------
__global__ __launch_bounds__(256) void k_in(const float* __restrict__ X,
                                            const float* __restrict__ W,
                                            const float* __restrict__ b,
                                            bfu* __restrict__ hout) {
    __shared__ float xs[32][FP];
    const int t = threadIdx.x;
    const int row0 = blockIdx.x * 32;
    for (int i = t; i < 32 * F; i += 256) {
        int r = i / F, f = i - r * F;
        xs[r][f] = X[(row0 + r) * F + f];
    }
    __syncthreads();
    float acc[32];
#pragma unroll
    for (int r = 0; r < 32; ++r) acc[r] = 0.f;
    for (int f = 0; f < 132; f += 4) {
        float w0 = W[(f + 0) * H + t];
        float w1 = W[(f + 1) * H + t];
        float w2 = W[(f + 2) * H + t];
        float w3 = W[(f + 3) * H + t];
#pragma unroll
        for (int r = 0; r < 32; ++r) {
            float4 xv = *reinterpret_cast<const float4*>(&xs[r][f]);
            acc[r] = fmaf(xv.x, w0, acc[r]);
            acc[r] = fmaf(xv.y, w1, acc[r]);
            acc[r] = fmaf(xv.z, w2, acc[r]);
            acc[r] = fmaf(xv.w, w3, acc[r]);
        }
    }
    {
        float w0 = W[132 * H + t];
#pragma unroll
        for (int r = 0; r < 32; ++r) acc[r] = fmaf(xs[r][132], w0, acc[r]);
    }
    float bb = b[t];
#pragma unroll
    for (int r = 0; r < 32; ++r) hout[(row0 + r) * H + t] = f2bf(acc[r] + bb);
}

// ---------------- sparse index build + zero the readout barriers ----------------
__global__ __launch_bounds__(256) void k_scan(const float4* __restrict__ A4,
                                              int* __restrict__ cnt,
                                              int* __restrict__ colidx,
                                              int* __restrict__ bars) {
    if (blockIdx.x == 0 && threadIdx.x < 16) bars[threadIdx.x] = 0;
    const int wave = threadIdx.x >> 6;
    const int lane = threadIdx.x & 63;
    const int row = blockIdx.x * 4 + wave;
    const float4* rowp = A4 + (size_t)row * (N / 4);
    const unsigned long long lmask = (1ull << lane) - 1ull;
    int base = 0;
    int* rowout = colidx + row * MAXDEG;
    for (int it = 0; it < N / 4 / 64; ++it) {
        float4 v = rowp[it * 64 + lane];
        int col0 = (it * 64 + lane) * 4;
        float vv[4] = {v.x, v.y, v.z, v.w};
#pragma unroll
        for (int c = 0; c < 4; ++c) {
            bool nz = (vv[c] != 0.0f);
            unsigned long long m = __ballot(nz);
            if (nz) {
                int pos = base + __popcll(m & lmask);
                if (pos < MAXDEG) rowout[pos] = col0 + c;
            }
            base += __popcll(m);
        }
    }
    if (lane == 0) cnt[row] = base < MAXDEG ? base : MAXDEG;
}

// ---------------- attention scores for h0 ----------------
__global__ __launch_bounds__(256) void k_scores(const bfu* __restrict__ h,
                                                const float* __restrict__ Watt,
                                                float* __restrict__ s_nei,
                                                float* __restrict__ s_self) {
    const int lane = threadIdx.x & 63;
    const int wave = threadIdx.x >> 6;
    const int row = blockIdx.x * 4 + wave;
    const ushort4 hv = *reinterpret_cast<const ushort4*>(&h[row * H + lane * 4]);
    const float4 wn = *reinterpret_cast<const float4*>(&Watt[lane * 4]);
    const float4 ws = *reinterpret_cast<const float4*>(&Watt[H + lane * 4]);
    float h0 = bf2f(hv.x), h1 = bf2f(hv.y), h2 = bf2f(hv.z), h3 = bf2f(hv.w);
    float an = h0 * wn.x + h1 * wn.y + h2 * wn.z + h3 * wn.w;
    float as = h0 * ws.x + h1 * ws.y + h2 * ws.z + h3 * ws.w;
    for (int off = 32; off > 0; off >>= 1) {
        an += __shfl_down(an, off);
        as += __shfl_down(as, off);
    }
    if (lane == 0) { s_nei[row] = an; s_self[row] = as; }
}

// ---------------- fused depth: weights -> gather-agg(LDS) -> GEMM -> relu/bf16
//                  + scores of new h (row-local) OR colsum partials (last depth)
template <bool LAST>
__global__ __launch_bounds__(256) void k_depth(
    const bfu* __restrict__ hin, bfu* __restrict__ hout,
    const int* __restrict__ cnt, const int* __restrict__ colidx,
    const float* __restrict__ snei_in, const float* __restrict__ sself_in,
    float* __restrict__ snei_out, float* __restrict__ sself_out,
    const float* __restrict__ Wn, const float* __restrict__ bn,
    const float* __restrict__ Watt, const float* __restrict__ b_att,
    float* __restrict__ part) {
    __shared__ float hgT[256][33];     // [k][m], pad 33: conflict-free b32 reads
    __shared__ float uni[8192];        // 32 KB: wls+jls (ph0/1) then Ws (ph2)
    __shared__ float sred[2048];       // 8 KB tail scratch
    __shared__ float sselfL[32];
    __shared__ int ncnt[32];
    float* wls = uni;                              // [32][128]
    int*   jls = (int*)(uni + 4096);               // [32][128]
    float* Ws  = uni;                              // [32][256]
    const int t = threadIdx.x;
    const int R0 = blockIdx.x * 32;

    // ---- phase 0: sigmoid weights ----
    if (t < 32) { ncnt[t] = cnt[R0 + t]; sselfL[t] = sself_in[R0 + t] + b_att[0]; }
    __syncthreads();
    for (int rep = 0; rep < 16; ++rep) {
        int idx = t + rep * 256;
        int r = idx >> 7, k = idx & 127;
        if (k < ncnt[r]) {
            int j = colidx[(R0 + r) * MAXDEG + k];
            jls[r * 128 + k] = j;
            wls[r * 128 + k] = 1.f / (1.f + __expf(-(sselfL[r] + snei_in[j])));
        }
    }
    __syncthreads();

    // ---- phase 1: gather-aggregate, write hgT[k][m] ----
    {
        const int w = t >> 6, l = t & 63;
#define GSTEP(u, sx, sy, sz, sw)                                                  \
        { int ju = jls[r * 128 + k + u]; float wv = wls[r * 128 + k + u];         \
          ushort4 hv = *reinterpret_cast<const ushort4*>(&hin[ju * 256 + (l << 2)]); \
          sx = fmaf(wv, bf2f(hv.x), sx); sy = fmaf(wv, bf2f(hv.y), sy);           \
          sz = fmaf(wv, bf2f(hv.z), sz); sw = fmaf(wv, bf2f(hv.w), sw); }
        for (int rr = 0; rr < 8; ++rr) {
            int r = rr * 4 + w;
            int n = ncnt[r];
            float x0=0,y0=0,z0=0,w0=0, x1=0,y1=0,z1=0,w1=0;
            float x2=0,y2=0,z2=0,w2=0, x3=0,y3=0,z3=0,w3=0;
            float x4=0,y4=0,z4=0,w4=0, x5=0,y5=0,z5=0,w5=0;
            float x6=0,y6=0,z6=0,w6=0, x7=0,y7=0,z7=0,w7=0;
            int k = 0;
            for (; k + 8 <= n; k += 8) {
                GSTEP(0,x0,y0,z0,w0) GSTEP(1,x1,y1,z1,w1)
                GSTEP(2,x2,y2,z2,w2) GSTEP(3,x3,y3,z3,w3)
                GSTEP(4,x4,y4,z4,w4) GSTEP(5,x5,y5,z5,w5)
                GSTEP(6,x6,y6,z6,w6) GSTEP(7,x7,y7,z7,w7)
            }
            for (; k < n; ++k) { GSTEP(0,x0,y0,z0,w0) }
            float fx = ((x0+x1)+(x2+x3)) + ((x4+x5)+(x6+x7));
            float fy = ((y0+y1)+(y2+y3)) + ((y4+y5)+(y6+y7));
            float fz = ((z0+z1)+(z2+z3)) + ((z4+z5)+(z6+z7));
            float fw = ((w0+w1)+(w2+w3)) + ((w4+w5)+(w6+w7));
            int c0 = l << 2;
            hgT[c0 + 0][r] = fx;
            hgT[c0 + 1][r] = fy;
            hgT[c0 + 2][r] = fz;
            hgT[c0 + 3][r] = fw;
        }
#undef GSTEP
    }

    // ---- phase 2: GEMM hg @ Wn, 32x256 output ----
    const int tx = t & 7, ty = t >> 3;      // tx->4 rows, ty->2 cols per bcol
    const int m0 = tx * 4;
    float acc[4][8];
#pragma unroll
    for (int i = 0; i < 4; ++i)
#pragma unroll
        for (int j = 0; j < 8; ++j) acc[i][j] = 0.f;

    for (int k0 = 0; k0 < 256; k0 += 32) {
        __syncthreads();   // protects hgT(first iter) / Ws readers(later iters)
#pragma unroll
        for (int rep = 0; rep < 8; ++rep) {
            int idx = t + rep * 256;
            int kr = idx >> 6, nc = (idx & 63) << 2;
            *reinterpret_cast<float4*>(&Ws[kr * 256 + nc]) =
                *reinterpret_cast<const float4*>(&Wn[(k0 + kr) * 256 + nc]);
        }
        __syncthreads();
#pragma unroll 8
        for (int kk = 0; kk < 32; ++kk) {
            int kg = k0 + kk;
            float a0 = hgT[kg][m0 + 0];
            float a1 = hgT[kg][m0 + 1];
            float a2 = hgT[kg][m0 + 2];
            float a3 = hgT[kg][m0 + 3];
#pragma unroll
            for (int bc = 0; bc < 4; ++bc) {
                float2 wv = *reinterpret_cast<const float2*>(&Ws[kk * 256 + bc * 64 + ty * 2]);
                acc[0][bc*2]   = fmaf(a0, wv.x, acc[0][bc*2]);
                acc[0][bc*2+1] = fmaf(a0, wv.y, acc[0][bc*2+1]);
                acc[1][bc*2]   = fmaf(a1, wv.x, acc[1][bc*2]);
                acc[1][bc*2+1] = fmaf(a1, wv.y, acc[1][bc*2+1]);
                acc[2][bc*2]   = fmaf(a2, wv.x, acc[2][bc*2]);
                acc[2][bc*2+1] = fmaf(a2, wv.y, acc[2][bc*2+1]);
                acc[3][bc*2]   = fmaf(a3, wv.x, acc[3][bc*2]);
                acc[3][bc*2+1] = fmaf(a3, wv.y, acc[3][bc*2+1]);
            }
        }
    }

    // ---- epilogue: bias + relu + bf16 store + fused tail ----
    float pn[4] = {0.f, 0.f, 0.f, 0.f};
    float ps[4] = {0.f, 0.f, 0.f, 0.f};
    float cs[8] = {0.f, 0.f, 0.f, 0.f, 0.f, 0.f, 0.f, 0.f};
#pragma unroll
    for (int bc = 0; bc < 4; ++bc) {
        const int c = bc * 64 + ty * 2;
        const float bb0 = bn[c], bb1 = bn[c + 1];
        float wan0 = 0, wan1 = 0, was0 = 0, was1 = 0;
        if (!LAST) {
            wan0 = Watt[c]; wan1 = Watt[c + 1];
            was0 = Watt[H + c]; was1 = Watt[H + c + 1];
        }
#pragma unroll
        for (int mi = 0; mi < 4; ++mi) {
            float v0 = acc[mi][bc*2] + bb0;
            float v1 = acc[mi][bc*2+1] + bb1;
            v0 = v0 > 0.f ? v0 : 0.f;
            v1 = v1 > 0.f ? v1 : 0.f;
            ushort2 o; o.x = f2bf(v0); o.y = f2bf(v1);
            *reinterpret_cast<ushort2*>(&hout[(R0 + m0 + mi) * 256 + c]) = o;
            if (!LAST) {
                pn[mi] = fmaf(v0, wan0, fmaf(v1, wan1, pn[mi]));
                ps[mi] = fmaf(v0, was0, fmaf(v1, was1, ps[mi]));
            } else {
                cs[bc*2]   += v0;
                cs[bc*2+1] += v1;
            }
        }
    }
    if (!LAST) {
        float* srN = sred;           // [ty(32)][m(32)]
        float* srS = sred + 1024;
#pragma unroll
        for (int mi = 0; mi < 4; ++mi) {
            srN[ty * 32 + m0 + mi] = pn[mi];
            srS[ty * 32 + m0 + mi] = ps[mi];
        }
        __syncthreads();
        if (t < 32) {
            float sn = 0.f, ss = 0.f;
            for (int q = 0; q < 32; ++q) {
                sn += srN[q * 32 + t];
                ss += srS[q * 32 + t];
            }
            snei_out[R0 + t] = sn;
            sself_out[R0 + t] = ss;
        }
    } else {
        float* srC = sred;           // [tx(8)][c(256)]
#pragma unroll
        for (int s8 = 0; s8 < 8; ++s8) {
            int bc = s8 >> 1, j = s8 & 1;
            srC[tx * 256 + bc * 64 + ty * 2 + j] = cs[s8];
        }
        __syncthreads();
        float s = 0.f;
#pragma unroll
        for (int q = 0; q < 8; ++q) s += srC[q * 256 + t];
        part[blockIdx.x * 256 + t] = s;
    }
}

// ---------------- fused readout: colsum-reduce + 3 MLP layers + dot ----------------
static __device__ __forceinline__ void dbar(int* bars, int i) {
    __threadfence();
    __syncthreads();
    if (threadIdx.x == 0) {
        atomicAdd(&bars[i], 1);
        while (atomicAdd(&bars[i], 0) < NRO_BLOCKS) { }
    }
    __syncthreads();
    __threadfence();
}

__global__ __launch_bounds__(256) void k_readout(
    const float* __restrict__ part, const float* __restrict__ mol,
    const float* __restrict__ W1, const float* __restrict__ b1,
    const float* __restrict__ Wh, const float* __restrict__ bh,
    const float* __restrict__ Wo, const float* __restrict__ bo,
    float* __restrict__ bpart, float* __restrict__ g1,
    float* __restrict__ g2, float* __restrict__ g3,
    int* bars, float* __restrict__ out) {
    __shared__ float xin[RH];
    __shared__ float red[256];
    const int t = threadIdx.x;
    const int blk = blockIdx.x;
    // stage 1: each block reduces 32 of the 256 partial rows
    {
        float s = 0.f;
        for (int r = 0; r < 32; ++r) s += part[(blk * 32 + r) * H + t];
        bpart[blk * H + t] = s;
    }
    dbar(bars, 0);
    {
        float s = 0.f;
#pragma unroll
        for (int i = 0; i < NRO_BLOCKS; ++i) s += bpart[i * H + t];
        xin[t] = s;
        if (t < MF) xin[H + t] = mol[t];
    }
    __syncthreads();
    const int o = blk * 64 + (t & 63);
    const int kg = t >> 6;
    // layer 1: K=456
    {
        float acc = 0.f;
        for (int k = kg; k < H + MF; k += 4) acc = fmaf(xin[k], W1[k * RH + o], acc);
        red[t] = acc;
        __syncthreads();
        if (t < 64) {
            float v = red[t] + red[t + 64] + red[t + 128] + red[t + 192] + b1[o];
            g1[o] = v > 0.f ? v : 0.f;
        }
    }
    dbar(bars, 1);
    __syncthreads();
    xin[t] = g1[t]; xin[t + 256] = g1[t + 256];
    __syncthreads();
    // layer 2: K=512
    {
        float acc = 0.f;
        for (int k = kg; k < RH; k += 4) acc = fmaf(xin[k], Wh[k * RH + o], acc);
        red[t] = acc;
        __syncthreads();
        if (t < 64) {
            float v = red[t] + red[t + 64] + red[t + 128] + red[t + 192] + bh[o];
            g2[o] = v > 0.f ? v : 0.f;
        }
    }
    dbar(bars, 2);
    __syncthreads();
    xin[t] = g2[t]; xin[t + 256] = g2[t + 256];
    __syncthreads();
    // layer 3: K=512
    {
        const float* Wh2 = Wh + RH * RH;
        float acc = 0.f;
        for (int k = kg; k < RH; k += 4) acc = fmaf(xin[k], Wh2[k * RH + o], acc);
        red[t] = acc;
        __syncthreads();
        if (t < 64) {
            float v = red[t] + red[t + 64] + red[t + 128] + red[t + 192] + bh[RH + o];
            g3[o] = v > 0.f ? v : 0.f;
        }
    }
    dbar(bars, 3);
    if (blk == 0) {
        red[t] = g3[t] * Wo[t] + g3[t + 256] * Wo[t + 256];
        __syncthreads();
        for (int s = 128; s > 0; s >>= 1) {
            if (t < s) red[t] += red[t + s];
            __syncthreads();
        }
        if (t == 0) out[0] = red[0] + bo[0];
    }
}

extern "C" void kernel_launch(void* const* d_in, const int* in_sizes, int n_in,
                              void* d_out, int out_size, void* d_ws, size_t ws_size,
                              hipStream_t stream) {
    const float* A        = (const float*)d_in[0];
    const float* X        = (const float*)d_in[1];
    const float* mol      = (const float*)d_in[2];
    const float* W_in     = (const float*)d_in[3];
    const float* b_in     = (const float*)d_in[4];
    const float* W_att    = (const float*)d_in[5];
    const float* b_att    = (const float*)d_in[6];
    const float* W_node   = (const float*)d_in[7];
    const float* b_node   = (const float*)d_in[8];
    const float* W_ro_in  = (const float*)d_in[9];
    const float* b_ro_in  = (const float*)d_in[10];
    const float* W_ro_hid = (const float*)d_in[11];
    const float* b_ro_hid = (const float*)d_in[12];
    const float* W_out    = (const float*)d_in[13];
    const float* b_out    = (const float*)d_in[14];

    char* ws = (char*)d_ws;
    bfu*   hb_a   = (bfu*)  (ws);                        // 4 MB
    bfu*   hb_b   = (bfu*)  (ws + 4194304);              // 4 MB
    int*   colidx = (int*)  (ws + 8388608);              // 4 MB
    int*   cnt    = (int*)  (ws + 12582912);             // 32 KB
    float* snei_a = (float*)(ws + 12615680);             // 32 KB
    float* sself_a= (float*)(ws + 12648448);             // 32 KB
    float* snei_b = (float*)(ws + 12681216);             // 32 KB
    float* sself_b= (float*)(ws + 12713984);             // 32 KB
    float* part   = (float*)(ws + 12746752);             // 256 KB
    float* bpart  = (float*)(ws + 13008896);             // 8 KB
    float* g1     = (float*)(ws + 13017088);             // 2 KB
    float* g2     = (float*)(ws + 13019136);             // 2 KB
    float* g3     = (float*)(ws + 13021184);             // 2 KB
    int*   bars   = (int*)  (ws + 13023232);             // 64 B

    // scan first: it also zeroes the readout barrier cells (stream order
    // guarantees this precedes k_readout on every replay)
    k_scan<<<N / 4, 256, 0, stream>>>((const float4*)A, cnt, colidx, bars);
    k_in<<<N / 32, 256, 0, stream>>>(X, W_in, b_in, hb_a);
    k_scores<<<N / 4, 256, 0, stream>>>(hb_a, W_att, snei_a, sself_a);

    // depth 0: a -> b, scores_a -> scores_b
    k_depth<false><<<N / 32, 256, 0, stream>>>(
        hb_a, hb_b, cnt, colidx, snei_a, sself_a, snei_b, sself_b,
        W_node + 0 * H * H, b_node + 0 * H, W_att, b_att, nullptr);
    // depth 1: b -> a, scores_b -> scores_a
    k_depth<false><<<N / 32, 256, 0, stream>>>(
        hb_b, hb_a, cnt, colidx, snei_b, sself_b, snei_a, sself_a,
        W_node + 1 * H * H, b_node + 1 * H, W_att, b_att, nullptr);
    // depth 2 (last): a -> b, emits colsum partials
    k_depth<true><<<N / 32, 256, 0, stream>>>(
        hb_a, hb_b, cnt, colidx, snei_a, sself_a, nullptr, nullptr,
        W_node + 2 * H * H, b_node + 2 * H, W_att, b_att, part);

    k_readout<<<NRO_BLOCKS, 256, 0, stream>>>(
        part, mol, W_ro_in, b_ro_in, W_ro_hid, b_ro_hid, W_out, b_out,
        bpart, g1, g2, g3, bars, (float*)d_out);
}

// Round 5
// 383.432 us; speedup vs baseline: 1.0802x; 1.0802x over previous
//
#include <hip/hip_runtime.h>
#include <hip/hip_bf16.h>
#include <math.h>

#define N 8192
#define F 133
#define FP 136
#define H 256
#define MF 200
#define RH 512
#define DEPTH 3
#define MAXDEG 128
#define IN_BLOCKS 256   // N/32

typedef unsigned short bfu;

static __device__ __forceinline__ bfu f2bf(float f) {
    unsigned u = __builtin_bit_cast(unsigned, f);
    u = (u + 0x7fff + ((u >> 16) & 1)) >> 16;   // RNE, finite inputs
    return (bfu)u;
}
static __device__ __forceinline__ float bf2f(bfu b) {
    unsigned u = (unsigned)b << 16;
    return __builtin_bit_cast(float, u);
}

// ---------------- fused front: h0-GEMM+scores (blocks 0..255) | A-scan (rest) ----
__global__ __launch_bounds__(256) void k_front(
    const float4* __restrict__ A4, int* __restrict__ cnt, int* __restrict__ colidx,
    const float* __restrict__ X, const float* __restrict__ Win,
    const float* __restrict__ bin, const float* __restrict__ Watt,
    bfu* __restrict__ hout, float* __restrict__ snei, float* __restrict__ sself) {
    const int t = threadIdx.x;
    if (blockIdx.x >= IN_BLOCKS) {
        // ---- A-scan: wave-per-row ballot compaction ----
        const int wave = t >> 6;
        const int lane = t & 63;
        const int row = (blockIdx.x - IN_BLOCKS) * 4 + wave;
        const float4* rowp = A4 + (size_t)row * (N / 4);
        const unsigned long long lmask = (1ull << lane) - 1ull;
        int base = 0;
        int* rowout = colidx + row * MAXDEG;
        for (int it = 0; it < N / 4 / 64; ++it) {
            float4 v = rowp[it * 64 + lane];
            int col0 = (it * 64 + lane) * 4;
            float vv[4] = {v.x, v.y, v.z, v.w};
#pragma unroll
            for (int c = 0; c < 4; ++c) {
                bool nz = (vv[c] != 0.0f);
                unsigned long long m = __ballot(nz);
                if (nz) {
                    int pos = base + __popcll(m & lmask);
                    if (pos < MAXDEG) rowout[pos] = col0 + c;
                }
                base += __popcll(m);
            }
        }
        if (lane == 0) cnt[row] = base < MAXDEG ? base : MAXDEG;
        return;
    }
    // ---- h0 = X @ W_in + b_in -> bf16, + attention scores of h0 ----
    __shared__ float xs[32][FP];
    __shared__ float sredN[32][4];
    __shared__ float sredS[32][4];
    const int row0 = blockIdx.x * 32;
    for (int i = t; i < 32 * F; i += 256) {
        int r = i / F, f = i - r * F;
        xs[r][f] = X[(row0 + r) * F + f];
    }
    __syncthreads();
    float acc[32];
#pragma unroll
    for (int r = 0; r < 32; ++r) acc[r] = 0.f;
    for (int f = 0; f < 132; f += 4) {
        float w0 = Win[(f + 0) * H + t];
        float w1 = Win[(f + 1) * H + t];
        float w2 = Win[(f + 2) * H + t];
        float w3 = Win[(f + 3) * H + t];
#pragma unroll
        for (int r = 0; r < 32; ++r) {
            float4 xv = *reinterpret_cast<const float4*>(&xs[r][f]);
            acc[r] = fmaf(xv.x, w0, acc[r]);
            acc[r] = fmaf(xv.y, w1, acc[r]);
            acc[r] = fmaf(xv.z, w2, acc[r]);
            acc[r] = fmaf(xv.w, w3, acc[r]);
        }
    }
    {
        float w0 = Win[132 * H + t];
#pragma unroll
        for (int r = 0; r < 32; ++r) acc[r] = fmaf(xs[r][132], w0, acc[r]);
    }
    const float bb = bin[t];
    const float wan = Watt[t];
    const float was = Watt[H + t];
    const int wv = t >> 6, ln = t & 63;
#pragma unroll
    for (int r = 0; r < 32; ++r) {
        float v = acc[r] + bb;
        hout[(row0 + r) * H + t] = f2bf(v);
        float pn = v * wan;
        float ps = v * was;
        for (int off = 32; off > 0; off >>= 1) {
            pn += __shfl_down(pn, off);
            ps += __shfl_down(ps, off);
        }
        if (ln == 0) { sredN[r][wv] = pn; sredS[r][wv] = ps; }
    }
    __syncthreads();
    if (t < 32)
        snei[row0 + t] = (sredN[t][0] + sredN[t][1]) + (sredN[t][2] + sredN[t][3]);
    else if (t < 64) {
        int r = t - 32;
        sself[row0 + r] = (sredS[r][0] + sredS[r][1]) + (sredS[r][2] + sredS[r][3]);
    }
}

// ---------------- fused depth: weights -> gather-agg(LDS) -> GEMM -> relu/bf16
//                  + scores of new h (row-local) OR colsum partials (last depth)
template <bool LAST>
__global__ __launch_bounds__(256) void k_depth(
    const bfu* __restrict__ hin, bfu* __restrict__ hout,
    const int* __restrict__ cnt, const int* __restrict__ colidx,
    const float* __restrict__ snei_in, const float* __restrict__ sself_in,
    float* __restrict__ snei_out, float* __restrict__ sself_out,
    const float* __restrict__ Wn, const float* __restrict__ bn,
    const float* __restrict__ Watt, const float* __restrict__ b_att,
    float* __restrict__ part) {
    __shared__ float hgT[256][33];     // [k][m], pad 33: conflict-free b32 reads
    __shared__ float uni[8192];        // 32 KB: wls+jls (ph0/1) then Ws (ph2)
    __shared__ float sred[2048];       // 8 KB tail scratch
    __shared__ float sselfL[32];
    __shared__ int ncnt[32];
    float* wls = uni;                              // [32][128]
    int*   jls = (int*)(uni + 4096);               // [32][128]
    float* Ws  = uni;                              // [32][256]
    const int t = threadIdx.x;
    const int R0 = blockIdx.x * 32;

    // ---- phase 0: sigmoid weights ----
    if (t < 32) { ncnt[t] = cnt[R0 + t]; sselfL[t] = sself_in[R0 + t] + b_att[0]; }
    __syncthreads();
    for (int rep = 0; rep < 16; ++rep) {
        int idx = t + rep * 256;
        int r = idx >> 7, k = idx & 127;
        if (k < ncnt[r]) {
            int j = colidx[(R0 + r) * MAXDEG + k];
            jls[r * 128 + k] = j;
            wls[r * 128 + k] = 1.f / (1.f + __expf(-(sselfL[r] + snei_in[j])));
        }
    }
    __syncthreads();

    // ---- phase 1: gather-aggregate, write hgT[k][m] ----
    {
        const int w = t >> 6, l = t & 63;
#define GSTEP(u, sx, sy, sz, sw)                                                  \
        { int ju = jls[r * 128 + k + u]; float wv = wls[r * 128 + k + u];         \
          ushort4 hv = *reinterpret_cast<const ushort4*>(&hin[ju * 256 + (l << 2)]); \
          sx = fmaf(wv, bf2f(hv.x), sx); sy = fmaf(wv, bf2f(hv.y), sy);           \
          sz = fmaf(wv, bf2f(hv.z), sz); sw = fmaf(wv, bf2f(hv.w), sw); }
        for (int rr = 0; rr < 8; ++rr) {
            int r = rr * 4 + w;
            int n = ncnt[r];
            float x0=0,y0=0,z0=0,w0=0, x1=0,y1=0,z1=0,w1=0;
            float x2=0,y2=0,z2=0,w2=0, x3=0,y3=0,z3=0,w3=0;
            float x4=0,y4=0,z4=0,w4=0, x5=0,y5=0,z5=0,w5=0;
            float x6=0,y6=0,z6=0,w6=0, x7=0,y7=0,z7=0,w7=0;
            int k = 0;
            for (; k + 8 <= n; k += 8) {
                GSTEP(0,x0,y0,z0,w0) GSTEP(1,x1,y1,z1,w1)
                GSTEP(2,x2,y2,z2,w2) GSTEP(3,x3,y3,z3,w3)
                GSTEP(4,x4,y4,z4,w4) GSTEP(5,x5,y5,z5,w5)
                GSTEP(6,x6,y6,z6,w6) GSTEP(7,x7,y7,z7,w7)
            }
            for (; k < n; ++k) { GSTEP(0,x0,y0,z0,w0) }
            float fx = ((x0+x1)+(x2+x3)) + ((x4+x5)+(x6+x7));
            float fy = ((y0+y1)+(y2+y3)) + ((y4+y5)+(y6+y7));
            float fz = ((z0+z1)+(z2+z3)) + ((z4+z5)+(z6+z7));
            float fw = ((w0+w1)+(w2+w3)) + ((w4+w5)+(w6+w7));
            int c0 = l << 2;
            hgT[c0 + 0][r] = fx;
            hgT[c0 + 1][r] = fy;
            hgT[c0 + 2][r] = fz;
            hgT[c0 + 3][r] = fw;
        }
#undef GSTEP
    }

    // ---- phase 2: GEMM hg @ Wn, 32x256 output ----
    const int tx = t & 7, ty = t >> 3;      // tx->4 rows, ty->2 cols per bcol
    const int m0 = tx * 4;
    float acc[4][8];
#pragma unroll
    for (int i = 0; i < 4; ++i)
#pragma unroll
        for (int j = 0; j < 8; ++j) acc[i][j] = 0.f;

    for (int k0 = 0; k0 < 256; k0 += 32) {
        __syncthreads();   // protects hgT(first iter) / Ws readers(later iters)
#pragma unroll
        for (int rep = 0; rep < 8; ++rep) {
            int idx = t + rep * 256;
            int kr = idx >> 6, nc = (idx & 63) << 2;
            *reinterpret_cast<float4*>(&Ws[kr * 256 + nc]) =
                *reinterpret_cast<const float4*>(&Wn[(k0 + kr) * 256 + nc]);
        }
        __syncthreads();
#pragma unroll 8
        for (int kk = 0; kk < 32; ++kk) {
            int kg = k0 + kk;
            float a0 = hgT[kg][m0 + 0];
            float a1 = hgT[kg][m0 + 1];
            float a2 = hgT[kg][m0 + 2];
            float a3 = hgT[kg][m0 + 3];
#pragma unroll
            for (int bc = 0; bc < 4; ++bc) {
                float2 wv = *reinterpret_cast<const float2*>(&Ws[kk * 256 + bc * 64 + ty * 2]);
                acc[0][bc*2]   = fmaf(a0, wv.x, acc[0][bc*2]);
                acc[0][bc*2+1] = fmaf(a0, wv.y, acc[0][bc*2+1]);
                acc[1][bc*2]   = fmaf(a1, wv.x, acc[1][bc*2]);
                acc[1][bc*2+1] = fmaf(a1, wv.y, acc[1][bc*2+1]);
                acc[2][bc*2]   = fmaf(a2, wv.x, acc[2][bc*2]);
                acc[2][bc*2+1] = fmaf(a2, wv.y, acc[2][bc*2+1]);
                acc[3][bc*2]   = fmaf(a3, wv.x, acc[3][bc*2]);
                acc[3][bc*2+1] = fmaf(a3, wv.y, acc[3][bc*2+1]);
            }
        }
    }

    // ---- epilogue: bias + relu + bf16 store + fused tail ----
    float pn[4] = {0.f, 0.f, 0.f, 0.f};
    float ps[4] = {0.f, 0.f, 0.f, 0.f};
    float cs[8] = {0.f, 0.f, 0.f, 0.f, 0.f, 0.f, 0.f, 0.f};
#pragma unroll
    for (int bc = 0; bc < 4; ++bc) {
        const int c = bc * 64 + ty * 2;
        const float bb0 = bn[c], bb1 = bn[c + 1];
        float wan0 = 0, wan1 = 0, was0 = 0, was1 = 0;
        if (!LAST) {
            wan0 = Watt[c]; wan1 = Watt[c + 1];
            was0 = Watt[H + c]; was1 = Watt[H + c + 1];
        }
#pragma unroll
        for (int mi = 0; mi < 4; ++mi) {
            float v0 = acc[mi][bc*2] + bb0;
            float v1 = acc[mi][bc*2+1] + bb1;
            v0 = v0 > 0.f ? v0 : 0.f;
            v1 = v1 > 0.f ? v1 : 0.f;
            ushort2 o; o.x = f2bf(v0); o.y = f2bf(v1);
            *reinterpret_cast<ushort2*>(&hout[(R0 + m0 + mi) * 256 + c]) = o;
            if (!LAST) {
                pn[mi] = fmaf(v0, wan0, fmaf(v1, wan1, pn[mi]));
                ps[mi] = fmaf(v0, was0, fmaf(v1, was1, ps[mi]));
            } else {
                cs[bc*2]   += v0;
                cs[bc*2+1] += v1;
            }
        }
    }
    if (!LAST) {
        float* srN = sred;           // [ty(32)][m(32)]
        float* srS = sred + 1024;
#pragma unroll
        for (int mi = 0; mi < 4; ++mi) {
            srN[ty * 32 + m0 + mi] = pn[mi];
            srS[ty * 32 + m0 + mi] = ps[mi];
        }
        __syncthreads();
        if (t < 32) {
            float sn = 0.f, ss = 0.f;
            for (int q = 0; q < 32; ++q) {
                sn += srN[q * 32 + t];
                ss += srS[q * 32 + t];
            }
            snei_out[R0 + t] = sn;
            sself_out[R0 + t] = ss;
        }
    } else {
        float* srC = sred;           // [tx(8)][c(256)]
#pragma unroll
        for (int s8 = 0; s8 < 8; ++s8) {
            int bc = s8 >> 1, j = s8 & 1;
            srC[tx * 256 + bc * 64 + ty * 2 + j] = cs[s8];
        }
        __syncthreads();
        float s = 0.f;
#pragma unroll
        for (int q = 0; q < 8; ++q) s += srC[q * 256 + t];
        part[blockIdx.x * 256 + t] = s;
    }
}

// ---------------- readout layer 1: g=[colsum, mol] (K=456) ----------------
__global__ __launch_bounds__(256) void k_ro1(const float* __restrict__ part,
                                             const float* __restrict__ mol,
                                             const float* __restrict__ W,
                                             const float* __restrict__ b,
                                             float* __restrict__ out) {
    __shared__ float xin[H + MF];
    __shared__ float red[256];
    const int t = threadIdx.x;
    {
        float s0 = 0.f, s1 = 0.f, s2 = 0.f, s3 = 0.f;
        for (int bb = 0; bb < 256; bb += 4) {
            s0 += part[(bb + 0) * H + t];
            s1 += part[(bb + 1) * H + t];
            s2 += part[(bb + 2) * H + t];
            s3 += part[(bb + 3) * H + t];
        }
        xin[t] = (s0 + s1) + (s2 + s3);
    }
    if (t < MF) xin[H + t] = mol[t];
    __syncthreads();
    const int o = blockIdx.x * 64 + (t & 63);
    const int kg = t >> 6;
    float acc = 0.f;
    for (int k = kg; k < H + MF; k += 4) acc = fmaf(xin[k], W[k * RH + o], acc);
    red[t] = acc;
    __syncthreads();
    if (t < 64) {
        float v = red[t] + red[t + 64] + red[t + 128] + red[t + 192] + b[o];
        out[o] = v > 0.f ? v : 0.f;
    }
}

// ---------------- readout hidden layer (K=512) ----------------
__global__ __launch_bounds__(256) void k_ro_hid(const float* __restrict__ g,
                                                const float* __restrict__ W,
                                                const float* __restrict__ b,
                                                float* __restrict__ out) {
    __shared__ float xin[RH];
    __shared__ float red[256];
    const int t = threadIdx.x;
    xin[t] = g[t];
    xin[t + 256] = g[t + 256];
    __syncthreads();
    const int o = blockIdx.x * 64 + (t & 63);
    const int kg = t >> 6;
    float acc = 0.f;
    for (int k = kg; k < RH; k += 4) acc = fmaf(xin[k], W[k * RH + o], acc);
    red[t] = acc;
    __syncthreads();
    if (t < 64) {
        float v = red[t] + red[t + 64] + red[t + 128] + red[t + 192] + b[o];
        out[o] = v > 0.f ? v : 0.f;
    }
}

// ---------------- final dot ----------------
__global__ __launch_bounds__(256) void k_out(const float* __restrict__ g,
                                             const float* __restrict__ W,
                                             const float* __restrict__ bo,
                                             float* __restrict__ out) {
    __shared__ float red[256];
    int t = threadIdx.x;
    red[t] = g[t] * W[t] + g[t + 256] * W[t + 256];
    __syncthreads();
    for (int s = 128; s > 0; s >>= 1) {
        if (t < s) red[t] += red[t + s];
        __syncthreads();
    }
    if (t == 0) out[0] = red[0] + bo[0];
}

extern "C" void kernel_launch(void* const* d_in, const int* in_sizes, int n_in,
                              void* d_out, int out_size, void* d_ws, size_t ws_size,
                              hipStream_t stream) {
    const float* A        = (const float*)d_in[0];
    const float* X        = (const float*)d_in[1];
    const float* mol      = (const float*)d_in[2];
    const float* W_in     = (const float*)d_in[3];
    const float* b_in     = (const float*)d_in[4];
    const float* W_att    = (const float*)d_in[5];
    const float* b_att    = (const float*)d_in[6];
    const float* W_node   = (const float*)d_in[7];
    const float* b_node   = (const float*)d_in[8];
    const float* W_ro_in  = (const float*)d_in[9];
    const float* b_ro_in  = (const float*)d_in[10];
    const float* W_ro_hid = (const float*)d_in[11];
    const float* b_ro_hid = (const float*)d_in[12];
    const float* W_out    = (const float*)d_in[13];
    const float* b_out    = (const float*)d_in[14];

    char* ws = (char*)d_ws;
    bfu*   hb_a   = (bfu*)  (ws);                        // 4 MB
    bfu*   hb_b   = (bfu*)  (ws + 4194304);              // 4 MB
    int*   colidx = (int*)  (ws + 8388608);              // 4 MB
    int*   cnt    = (int*)  (ws + 12582912);             // 32 KB
    float* snei_a = (float*)(ws + 12615680);             // 32 KB
    float* sself_a= (float*)(ws + 12648448);             // 32 KB
    float* snei_b = (float*)(ws + 12681216);             // 32 KB
    float* sself_b= (float*)(ws + 12713984);             // 32 KB
    float* part   = (float*)(ws + 12746752);             // 256 KB
    float* g1     = (float*)(ws + 13008896);             // 2 KB
    float* g2     = (float*)(ws + 13010944);             // 2 KB
    float* g3     = (float*)(ws + 13012992);             // 2 KB

    // fused front: blocks 0..255 compute h0+scores, blocks 256..2303 scan A
    k_front<<<IN_BLOCKS + N / 4, 256, 0, stream>>>(
        (const float4*)A, cnt, colidx, X, W_in, b_in, W_att, hb_a, snei_a, sself_a);

    // depth 0: a -> b, scores_a -> scores_b
    k_depth<false><<<N / 32, 256, 0, stream>>>(
        hb_a, hb_b, cnt, colidx, snei_a, sself_a, snei_b, sself_b,
        W_node + 0 * H * H, b_node + 0 * H, W_att, b_att, nullptr);
    // depth 1: b -> a, scores_b -> scores_a
    k_depth<false><<<N / 32, 256, 0, stream>>>(
        hb_b, hb_a, cnt, colidx, snei_b, sself_b, snei_a, sself_a,
        W_node + 1 * H * H, b_node + 1 * H, W_att, b_att, nullptr);
    // depth 2 (last): a -> b, emits colsum partials
    k_depth<true><<<N / 32, 256, 0, stream>>>(
        hb_a, hb_b, cnt, colidx, snei_a, sself_a, nullptr, nullptr,
        W_node + 2 * H * H, b_node + 2 * H, W_att, b_att, part);

    k_ro1<<<RH / 64, 256, 0, stream>>>(part, mol, W_ro_in, b_ro_in, g1);
    k_ro_hid<<<RH / 64, 256, 0, stream>>>(g1, W_ro_hid, b_ro_hid, g2);
    k_ro_hid<<<RH / 64, 256, 0, stream>>>(g2, W_ro_hid + RH * RH, b_ro_hid + RH, g3);
    k_out<<<1, 256, 0, stream>>>(g3, W_out, b_out, (float*)d_out);
}

// Round 6
// 362.434 us; speedup vs baseline: 1.1428x; 1.0579x over previous
//
#include <hip/hip_runtime.h>
#include <hip/hip_bf16.h>
#include <math.h>

#define N 8192
#define F 133
#define FP 136
#define H 256
#define MF 200
#define RH 512
#define DEPTH 3
#define MAXDEG 128
#define DROWS 16           // rows per k_depth block
#define DBLOCKS (N / DROWS)

typedef unsigned short bfu;

static __device__ __forceinline__ bfu f2bf(float f) {
    unsigned u = __builtin_bit_cast(unsigned, f);
    u = (u + 0x7fff + ((u >> 16) & 1)) >> 16;   // RNE, finite inputs
    return (bfu)u;
}
static __device__ __forceinline__ float bf2f(bfu b) {
    unsigned u = (unsigned)b << 16;
    return __builtin_bit_cast(float, u);
}

// ---------------- sparse index build: wave-per-row ballot compaction ----------------
__global__ __launch_bounds__(256) void k_scan(const float4* __restrict__ A4,
                                              int* __restrict__ cnt,
                                              int* __restrict__ colidx) {
    const int wave = threadIdx.x >> 6;
    const int lane = threadIdx.x & 63;
    const int row = blockIdx.x * 4 + wave;
    const float4* rowp = A4 + (size_t)row * (N / 4);
    const unsigned long long lmask = (1ull << lane) - 1ull;
    int base = 0;
    int* rowout = colidx + row * MAXDEG;
    for (int it = 0; it < N / 4 / 64; ++it) {
        float4 v = rowp[it * 64 + lane];
        int col0 = (it * 64 + lane) * 4;
        float vv[4] = {v.x, v.y, v.z, v.w};
#pragma unroll
        for (int c = 0; c < 4; ++c) {
            bool nz = (vv[c] != 0.0f);
            unsigned long long m = __ballot(nz);
            if (nz) {
                int pos = base + __popcll(m & lmask);
                if (pos < MAXDEG) rowout[pos] = col0 + c;
            }
            base += __popcll(m);
        }
    }
    if (lane == 0) cnt[row] = base < MAXDEG ? base : MAXDEG;
}

// ---------------- h0 = X @ W_in + b_in  -> bf16 ----------------
__global__ __launch_bounds__(256) void k_in(const float* __restrict__ X,
                                            const float* __restrict__ W,
                                            const float* __restrict__ b,
                                            bfu* __restrict__ hout) {
    __shared__ float xs[32][FP];
    const int t = threadIdx.x;
    const int row0 = blockIdx.x * 32;
    for (int i = t; i < 32 * F; i += 256) {
        int r = i / F, f = i - r * F;
        xs[r][f] = X[(row0 + r) * F + f];
    }
    __syncthreads();
    float acc[32];
#pragma unroll
    for (int r = 0; r < 32; ++r) acc[r] = 0.f;
    for (int f = 0; f < 132; f += 4) {
        float w0 = W[(f + 0) * H + t];
        float w1 = W[(f + 1) * H + t];
        float w2 = W[(f + 2) * H + t];
        float w3 = W[(f + 3) * H + t];
#pragma unroll
        for (int r = 0; r < 32; ++r) {
            float4 xv = *reinterpret_cast<const float4*>(&xs[r][f]);
            acc[r] = fmaf(xv.x, w0, acc[r]);
            acc[r] = fmaf(xv.y, w1, acc[r]);
            acc[r] = fmaf(xv.z, w2, acc[r]);
            acc[r] = fmaf(xv.w, w3, acc[r]);
        }
    }
    {
        float w0 = W[132 * H + t];
#pragma unroll
        for (int r = 0; r < 32; ++r) acc[r] = fmaf(xs[r][132], w0, acc[r]);
    }
    float bb = b[t];
#pragma unroll
    for (int r = 0; r < 32; ++r) hout[(row0 + r) * H + t] = f2bf(acc[r] + bb);
}

// ---------------- attention scores for h0 ----------------
__global__ __launch_bounds__(256) void k_scores(const bfu* __restrict__ h,
                                                const float* __restrict__ Watt,
                                                float* __restrict__ s_nei,
                                                float* __restrict__ s_self) {
    const int lane = threadIdx.x & 63;
    const int wave = threadIdx.x >> 6;
    const int row = blockIdx.x * 4 + wave;
    const ushort4 hv = *reinterpret_cast<const ushort4*>(&h[row * H + lane * 4]);
    const float4 wn = *reinterpret_cast<const float4*>(&Watt[lane * 4]);
    const float4 ws = *reinterpret_cast<const float4*>(&Watt[H + lane * 4]);
    float h0 = bf2f(hv.x), h1 = bf2f(hv.y), h2 = bf2f(hv.z), h3 = bf2f(hv.w);
    float an = h0 * wn.x + h1 * wn.y + h2 * wn.z + h3 * wn.w;
    float as = h0 * ws.x + h1 * ws.y + h2 * ws.z + h3 * ws.w;
    for (int off = 32; off > 0; off >>= 1) {
        an += __shfl_down(an, off);
        as += __shfl_down(as, off);
    }
    if (lane == 0) { s_nei[row] = an; s_self[row] = as; }
}

// ---------------- fused depth, 16 rows/block, 512 blocks (2 blocks/CU) -------
// hgT layout: feature k of row m at hgT[(k>>2)*68 + m*4 + (k&3)]
//  -> gather lane writes ONE b128 (banks (17l+r)%32, 2-way = free)
//  -> GEMM A-reads are whole-wave broadcasts (free)
template <bool LAST>
__global__ __launch_bounds__(256) void k_depth(
    const bfu* __restrict__ hin, bfu* __restrict__ hout,
    const int* __restrict__ cnt, const int* __restrict__ colidx,
    const float* __restrict__ snei_in, const float* __restrict__ sself_in,
    float* __restrict__ snei_out, float* __restrict__ sself_out,
    const float* __restrict__ Wn, const float* __restrict__ bn,
    const float* __restrict__ Watt, const float* __restrict__ b_att,
    float* __restrict__ part) {
    __shared__ float hgT[64 * 68];        // 17408 B
    __shared__ float wls[DROWS * 128];    // 8 KB
    __shared__ int   jls[DROWS * 128];    // 8 KB
    __shared__ float csred[4 * 256];      // 4 KB (LAST only use)
    __shared__ float sselfL[DROWS];
    __shared__ int   ncnt[DROWS];
    const int t = threadIdx.x;
    const int w = t >> 6, l = t & 63;
    const int R0 = blockIdx.x * DROWS;

    if (t < DROWS) { ncnt[t] = cnt[R0 + t]; sselfL[t] = sself_in[R0 + t] + b_att[0]; }
    __syncthreads();
    // ---- phase 0: sigmoid weights (2048 slots) ----
#pragma unroll
    for (int rep = 0; rep < 8; ++rep) {
        int idx = t + rep * 256;
        int r = idx >> 7, k = idx & 127;
        if (k < ncnt[r]) {
            int j = colidx[(R0 + r) * MAXDEG + k];
            jls[idx] = j;
            wls[idx] = 1.f / (1.f + __expf(-(sselfL[r] + snei_in[j])));
        }
    }
    __syncthreads();

    // ---- phase 1: gather-aggregate; wave w owns rows 4w..4w+3 ----
    {
#define GSTEP(u, sx, sy, sz, sw)                                                  \
        { int ju = jls[r * 128 + k + u]; float wv = wls[r * 128 + k + u];         \
          ushort4 hv = *reinterpret_cast<const ushort4*>(&hin[ju * 256 + (l << 2)]); \
          sx = fmaf(wv, bf2f(hv.x), sx); sy = fmaf(wv, bf2f(hv.y), sy);           \
          sz = fmaf(wv, bf2f(hv.z), sz); sw = fmaf(wv, bf2f(hv.w), sw); }
        for (int rr = 0; rr < 4; ++rr) {
            int r = w * 4 + rr;
            int n = ncnt[r];
            float x0=0,y0=0,z0=0,w0=0, x1=0,y1=0,z1=0,w1=0;
            float x2=0,y2=0,z2=0,w2=0, x3=0,y3=0,z3=0,w3=0;
            float x4=0,y4=0,z4=0,w4=0, x5=0,y5=0,z5=0,w5=0;
            float x6=0,y6=0,z6=0,w6=0, x7=0,y7=0,z7=0,w7=0;
            int k = 0;
            for (; k + 8 <= n; k += 8) {
                GSTEP(0,x0,y0,z0,w0) GSTEP(1,x1,y1,z1,w1)
                GSTEP(2,x2,y2,z2,w2) GSTEP(3,x3,y3,z3,w3)
                GSTEP(4,x4,y4,z4,w4) GSTEP(5,x5,y5,z5,w5)
                GSTEP(6,x6,y6,z6,w6) GSTEP(7,x7,y7,z7,w7)
            }
            for (; k < n; ++k) { GSTEP(0,x0,y0,z0,w0) }
            float4 st;
            st.x = ((x0+x1)+(x2+x3)) + ((x4+x5)+(x6+x7));
            st.y = ((y0+y1)+(y2+y3)) + ((y4+y5)+(y6+y7));
            st.z = ((z0+z1)+(z2+z3)) + ((z4+z5)+(z6+z7));
            st.w = ((w0+w1)+(w2+w3)) + ((w4+w5)+(w6+w7));
            *reinterpret_cast<float4*>(&hgT[l * 68 + r * 4]) = st;
        }
#undef GSTEP
    }
    __syncthreads();

    // ---- phase 2: GEMM (16 x 256) = hgT^T @ Wn; thread = rows 4w..4w+3, cols 4l..4l+3
    float acc[4][4];
#pragma unroll
    for (int i = 0; i < 4; ++i)
#pragma unroll
        for (int j = 0; j < 4; ++j) acc[i][j] = 0.f;
    const int c0 = l << 2;
#pragma unroll 2
    for (int k4 = 0; k4 < 64; ++k4) {
        const float* hp = &hgT[k4 * 68 + 16 * w];
#pragma unroll
        for (int ki = 0; ki < 4; ++ki) {
            int kk = k4 * 4 + ki;
            float4 wv = *reinterpret_cast<const float4*>(&Wn[kk * 256 + c0]);
            float a0 = hp[0 * 4 + ki];
            float a1 = hp[1 * 4 + ki];
            float a2 = hp[2 * 4 + ki];
            float a3 = hp[3 * 4 + ki];
            acc[0][0] = fmaf(a0, wv.x, acc[0][0]); acc[0][1] = fmaf(a0, wv.y, acc[0][1]);
            acc[0][2] = fmaf(a0, wv.z, acc[0][2]); acc[0][3] = fmaf(a0, wv.w, acc[0][3]);
            acc[1][0] = fmaf(a1, wv.x, acc[1][0]); acc[1][1] = fmaf(a1, wv.y, acc[1][1]);
            acc[1][2] = fmaf(a1, wv.z, acc[1][2]); acc[1][3] = fmaf(a1, wv.w, acc[1][3]);
            acc[2][0] = fmaf(a2, wv.x, acc[2][0]); acc[2][1] = fmaf(a2, wv.y, acc[2][1]);
            acc[2][2] = fmaf(a2, wv.z, acc[2][2]); acc[2][3] = fmaf(a2, wv.w, acc[2][3]);
            acc[3][0] = fmaf(a3, wv.x, acc[3][0]); acc[3][1] = fmaf(a3, wv.y, acc[3][1]);
            acc[3][2] = fmaf(a3, wv.z, acc[3][2]); acc[3][3] = fmaf(a3, wv.w, acc[3][3]);
        }
    }

    // ---- epilogue: bias + relu + bf16 store + scores (shfl) or colsum ----
    const float4 bv = *reinterpret_cast<const float4*>(&bn[c0]);
    float4 wanv, wasv;
    if (!LAST) {
        wanv = *reinterpret_cast<const float4*>(&Watt[c0]);
        wasv = *reinterpret_cast<const float4*>(&Watt[H + c0]);
    }
    float cs0 = 0.f, cs1 = 0.f, cs2 = 0.f, cs3 = 0.f;
#pragma unroll
    for (int i = 0; i < 4; ++i) {
        float v0 = acc[i][0] + bv.x; v0 = v0 > 0.f ? v0 : 0.f;
        float v1 = acc[i][1] + bv.y; v1 = v1 > 0.f ? v1 : 0.f;
        float v2 = acc[i][2] + bv.z; v2 = v2 > 0.f ? v2 : 0.f;
        float v3 = acc[i][3] + bv.w; v3 = v3 > 0.f ? v3 : 0.f;
        ushort4 o; o.x = f2bf(v0); o.y = f2bf(v1); o.z = f2bf(v2); o.w = f2bf(v3);
        *reinterpret_cast<ushort4*>(&hout[(R0 + w * 4 + i) * H + c0]) = o;
        if (!LAST) {
            float pn = v0 * wanv.x + v1 * wanv.y + v2 * wanv.z + v3 * wanv.w;
            float ps = v0 * wasv.x + v1 * wasv.y + v2 * wasv.z + v3 * wasv.w;
#pragma unroll
            for (int off = 32; off > 0; off >>= 1) {
                pn += __shfl_xor(pn, off);
                ps += __shfl_xor(ps, off);
            }
            if (l == 0) {
                snei_out[R0 + w * 4 + i] = pn;
                sself_out[R0 + w * 4 + i] = ps;
            }
        } else {
            cs0 += v0; cs1 += v1; cs2 += v2; cs3 += v3;
        }
    }
    if (LAST) {
        csred[w * 256 + c0 + 0] = cs0;
        csred[w * 256 + c0 + 1] = cs1;
        csred[w * 256 + c0 + 2] = cs2;
        csred[w * 256 + c0 + 3] = cs3;
        __syncthreads();
        part[blockIdx.x * H + t] =
            (csred[t] + csred[256 + t]) + (csred[512 + t] + csred[768 + t]);
    }
}

// ---------------- readout layer 1: g=[colsum(512 parts), mol] (K=456) ----------------
__global__ __launch_bounds__(256) void k_ro1(const float* __restrict__ part,
                                             const float* __restrict__ mol,
                                             const float* __restrict__ W,
                                             const float* __restrict__ b,
                                             float* __restrict__ out) {
    __shared__ float xin[H + MF];
    __shared__ float red[256];
    const int t = threadIdx.x;
    {
        float s0 = 0.f, s1 = 0.f, s2 = 0.f, s3 = 0.f;
        for (int bb = 0; bb < DBLOCKS; bb += 4) {
            s0 += part[(bb + 0) * H + t];
            s1 += part[(bb + 1) * H + t];
            s2 += part[(bb + 2) * H + t];
            s3 += part[(bb + 3) * H + t];
        }
        xin[t] = (s0 + s1) + (s2 + s3);
    }
    if (t < MF) xin[H + t] = mol[t];
    __syncthreads();
    const int o = blockIdx.x * 64 + (t & 63);
    const int kg = t >> 6;
    float acc = 0.f;
    for (int k = kg; k < H + MF; k += 4) acc = fmaf(xin[k], W[k * RH + o], acc);
    red[t] = acc;
    __syncthreads();
    if (t < 64) {
        float v = red[t] + red[t + 64] + red[t + 128] + red[t + 192] + b[o];
        out[o] = v > 0.f ? v : 0.f;
    }
}

// ---------------- readout hidden layer (K=512) ----------------
__global__ __launch_bounds__(256) void k_ro_hid(const float* __restrict__ g,
                                                const float* __restrict__ W,
                                                const float* __restrict__ b,
                                                float* __restrict__ out) {
    __shared__ float xin[RH];
    __shared__ float red[256];
    const int t = threadIdx.x;
    xin[t] = g[t];
    xin[t + 256] = g[t + 256];
    __syncthreads();
    const int o = blockIdx.x * 64 + (t & 63);
    const int kg = t >> 6;
    float acc = 0.f;
    for (int k = kg; k < RH; k += 4) acc = fmaf(xin[k], W[k * RH + o], acc);
    red[t] = acc;
    __syncthreads();
    if (t < 64) {
        float v = red[t] + red[t + 64] + red[t + 128] + red[t + 192] + b[o];
        out[o] = v > 0.f ? v : 0.f;
    }
}

// ---------------- final dot ----------------
__global__ __launch_bounds__(256) void k_out(const float* __restrict__ g,
                                             const float* __restrict__ W,
                                             const float* __restrict__ bo,
                                             float* __restrict__ out) {
    __shared__ float red[256];
    int t = threadIdx.x;
    red[t] = g[t] * W[t] + g[t + 256] * W[t + 256];
    __syncthreads();
    for (int s = 128; s > 0; s >>= 1) {
        if (t < s) red[t] += red[t + s];
        __syncthreads();
    }
    if (t == 0) out[0] = red[0] + bo[0];
}

extern "C" void kernel_launch(void* const* d_in, const int* in_sizes, int n_in,
                              void* d_out, int out_size, void* d_ws, size_t ws_size,
                              hipStream_t stream) {
    const float* A        = (const float*)d_in[0];
    const float* X        = (const float*)d_in[1];
    const float* mol      = (const float*)d_in[2];
    const float* W_in     = (const float*)d_in[3];
    const float* b_in     = (const float*)d_in[4];
    const float* W_att    = (const float*)d_in[5];
    const float* b_att    = (const float*)d_in[6];
    const float* W_node   = (const float*)d_in[7];
    const float* b_node   = (const float*)d_in[8];
    const float* W_ro_in  = (const float*)d_in[9];
    const float* b_ro_in  = (const float*)d_in[10];
    const float* W_ro_hid = (const float*)d_in[11];
    const float* b_ro_hid = (const float*)d_in[12];
    const float* W_out    = (const float*)d_in[13];
    const float* b_out    = (const float*)d_in[14];

    char* ws = (char*)d_ws;
    bfu*   hb_a   = (bfu*)  (ws);                        // 4 MB
    bfu*   hb_b   = (bfu*)  (ws + 4194304);              // 4 MB
    int*   colidx = (int*)  (ws + 8388608);              // 4 MB
    int*   cnt    = (int*)  (ws + 12582912);             // 32 KB
    float* snei_a = (float*)(ws + 12615680);             // 32 KB
    float* sself_a= (float*)(ws + 12648448);             // 32 KB
    float* snei_b = (float*)(ws + 12681216);             // 32 KB
    float* sself_b= (float*)(ws + 12713984);             // 32 KB
    float* part   = (float*)(ws + 12746752);             // 512 KB
    float* g1     = (float*)(ws + 13271040);             // 2 KB
    float* g2     = (float*)(ws + 13273088);             // 2 KB
    float* g3     = (float*)(ws + 13275136);             // 2 KB

    k_scan<<<N / 4, 256, 0, stream>>>((const float4*)A, cnt, colidx);
    k_in<<<N / 32, 256, 0, stream>>>(X, W_in, b_in, hb_a);
    k_scores<<<N / 4, 256, 0, stream>>>(hb_a, W_att, snei_a, sself_a);

    // depth 0: a -> b, scores_a -> scores_b
    k_depth<false><<<DBLOCKS, 256, 0, stream>>>(
        hb_a, hb_b, cnt, colidx, snei_a, sself_a, snei_b, sself_b,
        W_node + 0 * H * H, b_node + 0 * H, W_att, b_att, nullptr);
    // depth 1: b -> a
    k_depth<false><<<DBLOCKS, 256, 0, stream>>>(
        hb_b, hb_a, cnt, colidx, snei_b, sself_b, snei_a, sself_a,
        W_node + 1 * H * H, b_node + 1 * H, W_att, b_att, nullptr);
    // depth 2 (last): a -> b, emits colsum partials
    k_depth<true><<<DBLOCKS, 256, 0, stream>>>(
        hb_a, hb_b, cnt, colidx, snei_a, sself_a, nullptr, nullptr,
        W_node + 2 * H * H, b_node + 2 * H, W_att, b_att, part);

    k_ro1<<<RH / 64, 256, 0, stream>>>(part, mol, W_ro_in, b_ro_in, g1);
    k_ro_hid<<<RH / 64, 256, 0, stream>>>(g1, W_ro_hid, b_ro_hid, g2);
    k_ro_hid<<<RH / 64, 256, 0, stream>>>(g2, W_ro_hid + RH * RH, b_ro_hid + RH, g3);
    k_out<<<1, 256, 0, stream>>>(g3, W_out, b_out, (float*)d_out);
}